// Round 2
// baseline (972.787 us; speedup 1.0000x reference)
//
#include <hip/hip_runtime.h>

typedef _Float16 half8 __attribute__((ext_vector_type(8)));
typedef float f32x4 __attribute__((ext_vector_type(4)));

// Block = 4 waves; wave e owns element e (B-frags in VGPRs, no LDS at all).
// Each wave: grid-stride over 64-atom tiles, full 64x256(K=128) -> 64x64 GEMM
// for its element via 16x16x32 f16 MFMA, epilogue ssp + W2-dot + butterfly,
// predicated atomicAdd for atoms whose zidx matches.
__global__ __launch_bounds__(256, 2)
void elemental_atomwise_kernel(const float* __restrict__ x,
                               const int* __restrict__ zidx,
                               const int* __restrict__ idx_m,
                               const float* __restrict__ W1,
                               const float* __restrict__ b1,
                               const float* __restrict__ W2,
                               const float* __restrict__ b2,
                               float* __restrict__ y,
                               int N, int ntiles) {
  const int lane = threadIdx.x & 63;
  const int e = threadIdx.x >> 6;  // wave id == element id
  const int c = lane & 15;         // 16-wide index (M for A/C, N-col for B)
  const int q = lane >> 4;         // quad

  // ---- one-time: B fragments for element e -> registers (fp16) ----
  // B[n][k] = W1[e][k][n]; frag: lane holds n = nt*16+c, k = kt*32+q*8+j
  half8 bf[4][4];  // [kt][nt]
#pragma unroll
  for (int kt = 0; kt < 4; ++kt)
#pragma unroll
    for (int nt = 0; nt < 4; ++nt) {
      const float* wp = W1 + e * 8192 + (kt * 32 + q * 8) * 64 + nt * 16 + c;
      half8 b;
#pragma unroll
      for (int j = 0; j < 8; ++j) b[j] = (_Float16)wp[j * 64];
      bf[kt][nt] = b;
    }
  float b1v[4], w2v[4];
#pragma unroll
  for (int nt = 0; nt < 4; ++nt) {
    b1v[nt] = b1[e * 64 + nt * 16 + c];
    w2v[nt] = W2[e * 64 + nt * 16 + c];
  }
  const float b2e = b2[e];

  for (int tile = blockIdx.x; tile < ntiles; tile += gridDim.x) {
    const long base = (long)tile * 64;

    // per-atom metadata (lane <-> atom within tile)
    long mi = base + lane;
    if (mi >= N) mi = N - 1;
    const int zm_l = zidx[mi];
    const int im_l = idx_m[mi];

    f32x4 acc[4][4];  // [mt][nt]
#pragma unroll
    for (int mt = 0; mt < 4; ++mt)
#pragma unroll
      for (int nt = 0; nt < 4; ++nt)
        acc[mt][nt] = (f32x4){0.f, 0.f, 0.f, 0.f};

#pragma unroll
    for (int kt = 0; kt < 4; ++kt) {
      half8 af[4];
#pragma unroll
      for (int mt = 0; mt < 4; ++mt) {
        long row = base + mt * 16 + c;
        if (row >= N) row = N - 1;
        const f32x4* rp = (const f32x4*)(x + row * 128);
        f32x4 u0 = rp[kt * 8 + q * 2];
        f32x4 u1 = rp[kt * 8 + q * 2 + 1];
        half8 a;
        a[0] = (_Float16)u0[0]; a[1] = (_Float16)u0[1];
        a[2] = (_Float16)u0[2]; a[3] = (_Float16)u0[3];
        a[4] = (_Float16)u1[0]; a[5] = (_Float16)u1[1];
        a[6] = (_Float16)u1[2]; a[7] = (_Float16)u1[3];
        af[mt] = a;
      }
#pragma unroll
      for (int nt = 0; nt < 4; ++nt)
#pragma unroll
        for (int mt = 0; mt < 4; ++mt)
          acc[mt][nt] = __builtin_amdgcn_mfma_f32_16x16x32_f16(
              af[mt], bf[kt][nt], acc[mt][nt], 0, 0, 0);
    }

    // ---- epilogue: ssp + layer-2 dot + 16-lane butterfly + predicated atomic ----
#pragma unroll
    for (int mt = 0; mt < 4; ++mt) {
#pragma unroll
      for (int i = 0; i < 4; ++i) {
        // C layout: col = c (hidden), row = q*4+i -> atom = base + mt*16 + q*4 + i
        float s = 0.0f;
#pragma unroll
        for (int nt = 0; nt < 4; ++nt) {
          float t = acc[mt][nt][i] + b1v[nt];
          float sp = __logf(1.0f + __expf(t)) - 0.69314718056f;  // shifted softplus
          s = fmaf(sp, w2v[nt], s);
        }
        s += __shfl_xor(s, 1);
        s += __shfl_xor(s, 2);
        s += __shfl_xor(s, 4);
        s += __shfl_xor(s, 8);
        const int mloc = mt * 16 + q * 4 + i;
        const int zm = __shfl(zm_l, mloc);
        const int im = __shfl(im_l, mloc);
        if (c == 0 && zm == e && base + mloc < N)
          atomicAdd(&y[im], s + b2e);
      }
    }
  }
}

extern "C" void kernel_launch(void* const* d_in, const int* in_sizes, int n_in,
                              void* d_out, int out_size, void* d_ws, size_t ws_size,
                              hipStream_t stream) {
  const float* x = (const float*)d_in[0];
  const int* zidx = (const int*)d_in[1];
  const int* idx_m = (const int*)d_in[2];
  const float* W1 = (const float*)d_in[3];
  const float* b1 = (const float*)d_in[4];
  const float* W2 = (const float*)d_in[5];
  const float* b2 = (const float*)d_in[6];
  float* y = (float*)d_out;

  const int N = in_sizes[0] / 128;
  const int ntiles = (N + 63) / 64;

  // y is accumulated with atomics: zero it first (d_out is poisoned 0xAA)
  hipMemsetAsync(d_out, 0, (size_t)out_size * sizeof(float), stream);

  int blocks = 512;  // 2 blocks/CU nominal; grid-stride covers all tiles
  if (blocks > ntiles) blocks = ntiles;

  elemental_atomwise_kernel<<<blocks, 256, 0, stream>>>(
      x, zidx, idx_m, W1, b1, W2, b2, y, N, ntiles);
}